// Round 1
// baseline (749.919 us; speedup 1.0000x reference)
//
#include <hip/hip_runtime.h>

// Hodgkin-Huxley synaptic network, semi-implicit (Crank-Nicolson) integration.
// One thread per (b, l) neuron chain; the t-loop is strictly sequential.
// B*L = 4096 threads = 64 wave64s. Lanes map to consecutive l -> coalesced
// 256B/wave z-loads and V-stores each step.

__global__ __launch_bounds__(64, 1)
void hh_kernel(const float* __restrict__ z, float* __restrict__ out, int N) {
    const int idx = blockIdx.x * 64 + threadIdx.x;   // 0 .. B*L-1
    const int b = idx >> 7;                          // / 128
    const int l = idx & 127;                         // % 128
    const size_t base = (size_t)b * N * 128 + l;
    const float* zp = z + base;
    float* op = out + base;

    float V = -70.0f, m = 0.0f, n = 0.0f, h = 1.0f, y = 0.0f;

    // t = 0 output: sigmoid((V - VT)/KP), VT=-20, KP=3
    op[0] = 1.0f / (1.0f + __expf((V + 20.0f) * (-1.0f / 3.0f)));

    float z_cur = zp[0];                 // z_prev for t=1
    for (int t = 1; t < N; ++t) {
        // prefetch next step's z (off critical path)
        float z_nxt = (t + 1 < N) ? zp[(size_t)t * 128] : 0.0f;

        // ---- membrane update ----
        float m2   = m * m;
        float pow1 = 40.0f * (m2 * m) * h;          // GNA * m^3 * h
        float n2   = n * n;
        float pow2 = 35.0f * (n2 * n2);             // GK * n^4
        float G = 0.025f * (pow1 + pow2 + 0.1f + 0.5f * y);   // DT/2 * (..+GL+GS*y)
        float E = pow1 * 55.0f + pow2 * -77.0f - 6.5f;        // +GL*EL; GS*VS*y==0
        float Vn = (V * (1.0f - G) + 0.05f * (E + 0.5f)) / (1.0f + G);

        // ---- gating rates (exp-sharing: b-rate exps are reciprocals of a-rate) ----
        float e1 = __expf((25.0f - Vn) * (1.0f / 9.0f));
        float aN = 0.02f * (Vn - 25.0f) / (1.0f - e1);
        float bN = 0.1f * e1 * aN;                  // == -0.002*(Vn-25)/(1-exp((Vn-25)/9))
        float e2 = __expf((-35.0f - Vn) * (1.0f / 9.0f));
        float aM = 0.182f * (Vn + 35.0f) / (1.0f - e2);
        float bM = 0.6813186813186813f * e2 * aM;   // 0.124/0.182
        float aH = 0.25f * __expf((-90.0f - Vn) * (1.0f / 12.0f));
        float bH = 0.25f * __expf((Vn + 34.0f) * (1.0f / 12.0f));
        // removable-singularity fixups (exact equality, as in reference);
        // without these our expressions are 0/0 -> NaN at these points.
        if (Vn == 25.0f)  { aN = 0.18f;  bN = 0.08f; }
        if (Vn == -35.0f) { aM = 1.638f; bM = 1.16f; }

        // ---- Crank-Nicolson gating updates ----
        float sM = 0.025f * (aM + bM);
        m = (aM * 0.05f + (1.0f - sM) * m) / (sM + 1.0f);
        float sN = 0.025f * (aN + bN);
        n = (aN * 0.05f + (1.0f - sN) * n) / (sN + 1.0f);
        float sH = 0.025f * (aH + bH);
        h = (aH * 0.05f + (1.0f - sH) * h) / (sH + 1.0f);
        // ---- synaptic gate ----
        float sy = 0.025f * (z_cur + 0.1f);         // DT/2*(A_D*z + A_R), A_D=1
        y = (z_cur * 0.05f + (1.0f - sy) * y) / (sy + 1.0f);

        V = Vn;
        op[(size_t)t * 128] = 1.0f / (1.0f + __expf((Vn + 20.0f) * (-1.0f / 3.0f)));
        z_cur = z_nxt;
    }
}

extern "C" void kernel_launch(void* const* d_in, const int* in_sizes, int n_in,
                              void* d_out, int out_size, void* d_ws, size_t ws_size,
                              hipStream_t stream) {
    const float* z = (const float*)d_in[0];
    float* out = (float*)d_out;
    const int B = 32, L = 128;
    const int N = in_sizes[0] / (B * L);             // 2000
    dim3 grid(B * L / 64), block(64);
    hipLaunchKernelGGL(hh_kernel, grid, block, 0, stream, z, out, N);
}

// Round 2
// 519.477 us; speedup vs baseline: 1.4436x; 1.4436x over previous
//
#include <hip/hip_runtime.h>

// Hodgkin-Huxley synaptic network, Crank-Nicolson integration.
// One thread per (b,l) chain; strictly serial t-loop, latency-bound (64 waves
// total -> ~1 wave/CU on 64 CUs). All divisions replaced with v_rcp_f32
// (1 ulp) + mul; algebra factored to shorten the loop-carried dependence:
//   G   = m3h + 0.875*n4 + 0.0025 + 0.0125*y          (GNA*DT/2 = 1 exactly)
//   DT*(E+IAPP) = 110*m3h - 134.75*n4 - 0.3
//   sN  = aN*(0.025 + 0.0025*e1)   since bN = 0.1*e1*aN
//   sM  = aM*(0.025 + 0.01703296703*e2)   since bM = (0.124/0.182)*e2*aM

__device__ __forceinline__ float rcpf(float x) { return __builtin_amdgcn_rcpf(x); }

__global__ __launch_bounds__(64, 1)
void hh_kernel(const float* __restrict__ z, float* __restrict__ out, int N) {
    const int idx = blockIdx.x * 64 + threadIdx.x;   // 0 .. B*L-1
    const int b = idx >> 7;                          // / 128
    const int l = idx & 127;                         // % 128
    const size_t base = (size_t)b * N * 128 + l;
    const float* zp = z + base;
    float* op = out + base;

    float V = -70.0f, m = 0.0f, n = 0.0f, h = 1.0f, y = 0.0f;

    // t = 0: sigmoid((V-VT)/KP), VT=-20, KP=3
    op[0] = rcpf(1.0f + __expf((V + 20.0f) * (-1.0f / 3.0f)));

    float z_cur = zp[0];
    for (int t = 1; t < N; ++t) {
        float z_nxt = zp[(size_t)t * 128];           // always in-bounds (t<=N-1)

        // ---- membrane update ----
        float m2 = m * m, mh = m * h;
        float p1 = m2 * mh;                          // m^3 h
        float n2 = n * n;
        float n4 = n2 * n2;
        float gy  = __builtin_fmaf(0.0125f, y, 0.0025f);
        float pg  = p1 + gy;
        float G   = __builtin_fmaf(0.875f, n4, pg);
        float den = G + 1.0f;
        float rd  = rcpf(den);                       // starts while num finishes
        float t1  = __builtin_fmaf(110.0f, p1, V - 0.3f);
        float t2  = __builtin_fmaf(-134.75f, n4, t1);
        float num = __builtin_fmaf(-V, G, t2);       // V*(1-G) + DT*(E+IAPP)
        float Vn  = num * rd;

        // ---- N gate ----
        float e1 = __expf((25.0f - Vn) * (1.0f / 9.0f));
        float r1 = rcpf(1.0f - e1);
        float aN = __builtin_fmaf(0.02f, Vn, -0.5f) * r1;    // 0.02*(Vn-25)/(1-e1)
        float gN = __builtin_fmaf(0.0025f, e1, 0.025f);      // 0.025*(1+0.1*e1)
        float sN = aN * gN;
        if (Vn == 25.0f) { aN = 0.18f; sN = 0.0065f; }       // 0.025*(0.18+0.08)
        float nm = __builtin_fmaf(-sN, n, n);
        float nn_ = __builtin_fmaf(0.05f, aN, nm) * rcpf(sN + 1.0f);

        // ---- M gate ----
        float e2 = __expf((-35.0f - Vn) * (1.0f / 9.0f));
        float r2 = rcpf(1.0f - e2);
        float aM = __builtin_fmaf(0.182f, Vn, 6.37f) * r2;   // 0.182*(Vn+35)/(1-e2)
        float gM = __builtin_fmaf(0.0170329670329670f, e2, 0.025f); // 0.025*(1+(0.124/0.182)e2)
        float sM = aM * gM;
        if (Vn == -35.0f) { aM = 1.638f; sM = 0.06995f; }    // 0.025*(1.638+1.16)
        float mm = __builtin_fmaf(-sM, m, m);
        m = __builtin_fmaf(0.05f, aM, mm) * rcpf(sM + 1.0f);

        // ---- H gate ----
        float aH = 0.25f * __expf((-90.0f - Vn) * (1.0f / 12.0f));
        float bH = 0.25f * __expf((Vn + 34.0f) * (1.0f / 12.0f));
        float sH = 0.025f * (aH + bH);
        float hm = __builtin_fmaf(-sH, h, h);
        h = __builtin_fmaf(0.05f, aH, hm) * rcpf(sH + 1.0f);

        // ---- synaptic gate (z-driven, off critical path) ----
        float sy = __builtin_fmaf(0.025f, z_cur, 0.0025f);
        float ym = __builtin_fmaf(-sy, y, y);
        y = __builtin_fmaf(0.05f, z_cur, ym) * rcpf(sy + 1.0f);

        n = nn_;
        V = Vn;
        op[(size_t)t * 128] = rcpf(1.0f + __expf((Vn + 20.0f) * (-1.0f / 3.0f)));
        z_cur = z_nxt;
    }
}

extern "C" void kernel_launch(void* const* d_in, const int* in_sizes, int n_in,
                              void* d_out, int out_size, void* d_ws, size_t ws_size,
                              hipStream_t stream) {
    const float* z = (const float*)d_in[0];
    float* out = (float*)d_out;
    const int B = 32, L = 128;
    const int N = in_sizes[0] / (B * L);             // 2000
    dim3 grid(B * L / 64), block(64);
    hipLaunchKernelGGL(hh_kernel, grid, block, 0, stream, z, out, N);
}

// Round 3
// 389.680 us; speedup vs baseline: 1.9244x; 1.3331x over previous
//
#include <hip/hip_runtime.h>

// Hodgkin-Huxley synaptic network, Crank-Nicolson integration.
// One thread per (b,l) chain; strictly serial t-loop, latency-bound.
// R2 lesson: 1-deep z prefetch < HBM latency (~900cy) -> per-step stall.
// R3: 4-deep rotating register prefetch + 4x unroll; exp args fused into
// exp2 form (v_exp_f32 IS exp2 -> saves the 1/ln2 mul per exp, 5/step).

__device__ __forceinline__ float rcpf(float x) { return __builtin_amdgcn_rcpf(x); }
__device__ __forceinline__ float ex2(float x) { return exp2f(x); }

// One CN step. Updates state in place, returns sigmoid((Vn-VT)/KP).
__device__ __forceinline__ float hh_step(float& V, float& m, float& n, float& h,
                                         float& y, float zc) {
    // ---- membrane ----
    float m2 = m * m, mh = m * h;
    float p1 = m2 * mh;                          // m^3 h   (GNA*DT/2 == 1)
    float n2 = n * n, n4 = n2 * n2;
    float gy = __builtin_fmaf(0.0125f, y, 0.0025f);
    float pg = p1 + gy;
    float G  = __builtin_fmaf(0.875f, n4, pg);
    float rd = rcpf(G + 1.0f);
    float t1 = __builtin_fmaf(110.0f, p1, V - 0.3f);
    float t2 = __builtin_fmaf(-134.75f, n4, t1);
    float num = __builtin_fmaf(-V, G, t2);       // V*(1-G) + DT*(E+IAPP)
    float Vn = num * rd;

    // ---- N gate ----  e1 = exp((25-Vn)/9) = exp2(fma(-c9,Vn,25*c9))
    float e1 = ex2(__builtin_fmaf(-0.16025096018360795f, Vn, 4.006274004590199f));
    float r1 = rcpf(1.0f - e1);
    float aN = __builtin_fmaf(0.02f, Vn, -0.5f) * r1;
    float sN = aN * __builtin_fmaf(0.0025f, e1, 0.025f);   // 0.025*(aN+bN)/aN form
    if (Vn == 25.0f) { aN = 0.18f; sN = 0.0065f; }
    n = __builtin_fmaf(0.05f, aN, __builtin_fmaf(-sN, n, n)) * rcpf(sN + 1.0f);

    // ---- M gate ----  e2 = exp((-35-Vn)/9)
    float e2 = ex2(__builtin_fmaf(-0.16025096018360795f, Vn, -5.608783606426278f));
    float r2 = rcpf(1.0f - e2);
    float aM = __builtin_fmaf(0.182f, Vn, 6.37f) * r2;
    float sM = aM * __builtin_fmaf(0.0170329670329670f, e2, 0.025f);
    if (Vn == -35.0f) { aM = 1.638f; sM = 0.06995f; }
    m = __builtin_fmaf(0.05f, aM, __builtin_fmaf(-sM, m, m)) * rcpf(sM + 1.0f);

    // ---- H gate ----  aH = 0.25*exp((-90-Vn)/12), bH = 0.25*exp((Vn+34)/12)
    float aH = 0.25f * ex2(__builtin_fmaf(-0.12018822013770593f, Vn, -10.816939812393534f));
    float bH = 0.25f * ex2(__builtin_fmaf( 0.12018822013770593f, Vn,   4.086399484682001f));
    float sH = 0.025f * (aH + bH);
    h = __builtin_fmaf(0.05f, aH, __builtin_fmaf(-sH, h, h)) * rcpf(sH + 1.0f);

    // ---- synaptic gate ----
    float sy = __builtin_fmaf(0.025f, zc, 0.0025f);
    y = __builtin_fmaf(0.05f, zc, __builtin_fmaf(-sy, y, y)) * rcpf(sy + 1.0f);

    V = Vn;
    // sigmoid((Vn+20)/3) = 1/(1+exp2(fma(-c3,Vn,-20*c3)))
    return rcpf(1.0f + ex2(__builtin_fmaf(-0.4807528805508243f, Vn, -9.615057611016486f)));
}

__global__ __launch_bounds__(64, 1)
void hh_kernel(const float* __restrict__ z, float* __restrict__ out, int N) {
    const int idx = blockIdx.x * 64 + threadIdx.x;   // 0 .. B*L-1
    const int b = idx >> 7;
    const int l = idx & 127;
    const size_t base = (size_t)b * N * 128 + l;
    const float* zp = z + base;
    float* op = out + base;

    float V = -70.0f, m = 0.0f, n = 0.0f, h = 1.0f, y = 0.0f;

    // t = 0 output
    op[0] = rcpf(1.0f + ex2(__builtin_fmaf(-0.4807528805508243f, V, -9.615057611016486f)));

    // 4-deep rotating prefetch: z0..z3 = z[t-1], z[t], z[t+1], z[t+2]
    float z0 = zp[0], z1 = zp[128], z2 = zp[256], z3 = zp[384];
    const float* zpre = zp + 4 * 128;                // next load: z[t+3] at t=1
    float* o = op + 128;
    int t = 1;
    // main: 4 steps/iter; prefetch indices t+3..t+6 must be <= N-1
    for (; t <= N - 7; t += 4) {
        float p0 = zpre[0];
        float p1 = zpre[128];
        float p2 = zpre[256];
        float p3 = zpre[384];
        zpre += 512;
        o[0]   = hh_step(V, m, n, h, y, z0);
        o[128] = hh_step(V, m, n, h, y, z1);
        o[256] = hh_step(V, m, n, h, y, z2);
        o[384] = hh_step(V, m, n, h, y, z3);
        o += 512;
        z0 = p0; z1 = p1; z2 = p2; z3 = p3;
    }
    // tail (<=6 steps), rotate through the register buffer
    for (; t < N; ++t) {
        *o = hh_step(V, m, n, h, y, z0);
        o += 128;
        z0 = z1; z1 = z2; z2 = z3;
    }
}

extern "C" void kernel_launch(void* const* d_in, const int* in_sizes, int n_in,
                              void* d_out, int out_size, void* d_ws, size_t ws_size,
                              hipStream_t stream) {
    const float* z = (const float*)d_in[0];
    float* out = (float*)d_out;
    const int B = 32, L = 128;
    const int N = in_sizes[0] / (B * L);             // 2000
    dim3 grid(B * L / 64), block(64);
    hipLaunchKernelGGL(hh_kernel, grid, block, 0, stream, z, out, N);
}